// Round 1
// baseline (3710.789 us; speedup 1.0000x reference)
//
#include <hip/hip_runtime.h>
#include <cstdint>
#include <cstddef>

#define BATCH    65536
#define CTXF     512
#define INF      514      // 512 ctx + 2 pos
#define HID      128
#define PREDL    12
#define OBSL     8
#define BM       64       // batch rows per block (lane == row)
#define NTHREADS 512      // 8 waves
#define NW       16       // output columns per wave (8*16 = 128)
#define LDSPAD   (HID + 1)

// tanh(x) = 1 - 2/(exp(2x)+1); v_exp + v_rcp, ~1e-6 rel err, saturates to +-1.
__device__ __forceinline__ float fast_tanh(float x) {
    float e = __expf(x + x);
    float r = __builtin_amdgcn_rcpf(e + 1.0f);
    return fmaf(-2.0f, r, 1.0f);
}

// acc[n] += sum_{k=0}^{HID-1} h[lane][k] * W[(n0+n)*ldw + k]
// n0 is wave-uniform -> all W accesses are scalar loads (SGPR broadcast).
__device__ __forceinline__ void mm16(float* __restrict__ acc,
                                     const float (* __restrict__ h)[LDSPAD],
                                     int lane,
                                     const float* __restrict__ W,
                                     int ldw, int n0)
{
#pragma unroll 1
    for (int k2 = 0; k2 < HID; k2 += 16) {
        float a[16];
#pragma unroll
        for (int j = 0; j < 16; ++j) a[j] = h[lane][k2 + j];
#pragma unroll
        for (int n = 0; n < NW; ++n) {
            const float* __restrict__ w = W + (size_t)(n0 + n) * ldw + k2;
#pragma unroll
            for (int j = 0; j < 16; ++j) acc[n] = fmaf(a[j], w[j], acc[n]);
        }
    }
}

__global__ void __launch_bounds__(NTHREADS)
rnn_head_kernel(const float* __restrict__ raw_ctx,
                const float* __restrict__ obs_traj,
                const float* __restrict__ Wih0, const float* __restrict__ Whh0,
                const float* __restrict__ bih0, const float* __restrict__ bhh0,
                const float* __restrict__ Wih1, const float* __restrict__ Whh1,
                const float* __restrict__ bih1, const float* __restrict__ bhh1,
                const float* __restrict__ Wih2, const float* __restrict__ Whh2,
                const float* __restrict__ bih2, const float* __restrict__ bhh2,
                const float* __restrict__ fcW,  const float* __restrict__ fcb,
                float* __restrict__ out)
{
    __shared__ float hs0[BM][LDSPAD];
    __shared__ float hs1[BM][LDSPAD];
    __shared__ float hs2[BM][LDSPAD];

    const int tid  = threadIdx.x;
    const int lane = tid & 63;
    const int wid  = __builtin_amdgcn_readfirstlane(tid >> 6);
    const int n0   = wid * NW;                 // wave-uniform column base
    const int row0 = blockIdx.x * BM;
    const int row  = row0 + lane;              // this lane's batch row

    // ---------------- Phase 1: ctx projection into registers ----------------
    // ctxb[n] = bih0[n0+n] + bhh0[n0+n] + sum_k raw_ctx[row][k]*Wih0[n0+n][k]
    float ctxb[NW];
#pragma unroll
    for (int n = 0; n < NW; ++n) ctxb[n] = bih0[n0 + n] + bhh0[n0 + n];

#pragma unroll 1
    for (int kc = 0; kc < CTXF; kc += HID) {
        __syncthreads();   // protect staging buffer reuse
        {   // stage raw_ctx[row0..row0+64)[kc..kc+128) into hs0 (coalesced)
            const int rr   = tid >> 3;          // 0..63
            const int cseg = (tid & 7) * 16;    // 0,16,...,112
            const float4* src = reinterpret_cast<const float4*>(
                raw_ctx + (size_t)(row0 + rr) * CTXF + kc + cseg);
            float4 v[4];
            v[0] = src[0]; v[1] = src[1]; v[2] = src[2]; v[3] = src[3];
            const float* vf = reinterpret_cast<const float*>(v);
#pragma unroll
            for (int j = 0; j < 16; ++j) hs0[rr][cseg + j] = vf[j];
        }
        __syncthreads();
        mm16(ctxb, hs0, lane, Wih0 + kc, INF, n0);
    }

    // ---------------- Phase 2: init state ----------------
    __syncthreads();
    for (int i = tid; i < BM * LDSPAD; i += NTHREADS) {
        (&hs0[0][0])[i] = 0.0f;
        (&hs1[0][0])[i] = 0.0f;
        (&hs2[0][0])[i] = 0.0f;
    }
    float2 pv = *reinterpret_cast<const float2*>(
        obs_traj + (size_t)(OBSL - 1) * BATCH * 2 + (size_t)row * 2);
    float p0 = pv.x, p1 = pv.y;
    const float fcb0 = fcb[0], fcb1 = fcb[1];
    __syncthreads();

    // ---------------- Phase 3: 12 recurrent steps ----------------
#pragma unroll 1
    for (int s = 0; s < PREDL; ++s) {
        float acc[NW];

        // ---- layer 0: h0 = tanh(ctxb + pos@Wp^T + h0_old@Whh0^T) ----
#pragma unroll
        for (int n = 0; n < NW; ++n) {
            float v = ctxb[n];
            v = fmaf(p0, Wih0[(size_t)(n0 + n) * INF + 512], v);
            v = fmaf(p1, Wih0[(size_t)(n0 + n) * INF + 513], v);
            acc[n] = v;
        }
        mm16(acc, hs0, lane, Whh0, HID, n0);
        __syncthreads();                                   // old h0 reads done
#pragma unroll
        for (int n = 0; n < NW; ++n) hs0[lane][n0 + n] = fast_tanh(acc[n]);
        __syncthreads();                                   // new h0 visible

        // ---- layer 1: h1 = tanh(h0@Wih1^T + b + h1_old@Whh1^T) ----
#pragma unroll
        for (int n = 0; n < NW; ++n) acc[n] = bih1[n0 + n] + bhh1[n0 + n];
        mm16(acc, hs0, lane, Wih1, HID, n0);
        mm16(acc, hs1, lane, Whh1, HID, n0);
        __syncthreads();
#pragma unroll
        for (int n = 0; n < NW; ++n) hs1[lane][n0 + n] = fast_tanh(acc[n]);
        __syncthreads();

        // ---- layer 2: h2 = tanh(h1@Wih2^T + b + h2_old@Whh2^T) ----
#pragma unroll
        for (int n = 0; n < NW; ++n) acc[n] = bih2[n0 + n] + bhh2[n0 + n];
        mm16(acc, hs1, lane, Wih2, HID, n0);
        mm16(acc, hs2, lane, Whh2, HID, n0);
        __syncthreads();
#pragma unroll
        for (int n = 0; n < NW; ++n) hs2[lane][n0 + n] = fast_tanh(acc[n]);
        __syncthreads();

        // ---- out = h2 @ fcW^T + fcb (each wave redundantly, for pos feedback) ----
        float o0 = fcb0, o1 = fcb1;
#pragma unroll 1
        for (int k2 = 0; k2 < HID; k2 += 16) {
            float a[16];
#pragma unroll
            for (int j = 0; j < 16; ++j) a[j] = hs2[lane][k2 + j];
#pragma unroll
            for (int j = 0; j < 16; ++j) {
                o0 = fmaf(a[j], fcW[k2 + j], o0);
                o1 = fmaf(a[j], fcW[HID + k2 + j], o1);
            }
        }
        if (wid == 0) {
            float2 ov; ov.x = o0; ov.y = o1;
            *reinterpret_cast<float2*>(out + ((size_t)s * BATCH + row) * 2) = ov;
        }
        p0 = o0; p1 = o1;  // feed_forward: cur_pos = output.detach()
    }
}

extern "C" void kernel_launch(void* const* d_in, const int* in_sizes, int n_in,
                              void* d_out, int out_size, void* d_ws, size_t ws_size,
                              hipStream_t stream)
{
    const float* raw_ctx  = (const float*)d_in[0];
    const float* obs_traj = (const float*)d_in[1];
    const float* Wih0 = (const float*)d_in[2];
    const float* Whh0 = (const float*)d_in[3];
    const float* bih0 = (const float*)d_in[4];
    const float* bhh0 = (const float*)d_in[5];
    const float* Wih1 = (const float*)d_in[6];
    const float* Whh1 = (const float*)d_in[7];
    const float* bih1 = (const float*)d_in[8];
    const float* bhh1 = (const float*)d_in[9];
    const float* Wih2 = (const float*)d_in[10];
    const float* Whh2 = (const float*)d_in[11];
    const float* bih2 = (const float*)d_in[12];
    const float* bhh2 = (const float*)d_in[13];
    const float* fcW  = (const float*)d_in[14];
    const float* fcb  = (const float*)d_in[15];
    float* out = (float*)d_out;

    dim3 grid(BATCH / BM);   // 1024 blocks
    dim3 block(NTHREADS);    // 512 threads = 8 waves
    rnn_head_kernel<<<grid, block, 0, stream>>>(
        raw_ctx, obs_traj,
        Wih0, Whh0, bih0, bhh0,
        Wih1, Whh1, bih1, bhh1,
        Wih2, Whh2, bih2, bhh2,
        fcW, fcb, out);
}

// Round 2
// 685.710 us; speedup vs baseline: 5.4116x; 5.4116x over previous
//
#include <hip/hip_runtime.h>
#include <cstdint>
#include <cstddef>

// PaperRNNHead on MI355X — MFMA split-bf16 persistent-weight design.
//
// Structure: 1024 blocks x 512 threads (8 waves). Block owns 64 batch rows.
// Wave w owns output-neuron slice n in [16w, 16w+16).
//  - All 5 recurrent weight matrices (Whh0, Wih1, Whh1, Wih2, Whh2) live in
//    VGPRs as bf16 hi/lo A-fragments (160 VGPRs) -> zero per-step weight loads.
//  - Hidden state h0/h1/h2 lives in LDS as separate hi/lo bf16 planes
//    [64 rows][136] (stride 272B: b128 reads are bank-balanced 8/bank = free).
//    Planes are read DIRECTLY as ds_read_b128 MFMA B-operands (no unpack).
//  - MFMA orientation: A = W[n][k], B = h[m][k], D = [n][m]. D-frag gives each
//    lane 4 consecutive n for one m -> h-writeback = v_cvt_pk_bf16_f32 pairs +
//    one b64 store per plane per tile.
//  - fp32 precision via 2-way split: x = hi + lo (bf16 each);
//    x*y ~= xh*yh + xh*yl + xl*yh  (3 MFMAs, ~2^-17 rel err/step).
//  - ctx @ Wih0[:, :512] is step-invariant: MFMA'd once at prologue into 16
//    VGPRs (ctxc) which seed layer-0's accumulator each step. pos terms (k=512,
//    513), biases, and the 128->2 fc are exact fp32 VALU.

#define BATCH    65536
#define CTXF     512
#define INF      514
#define HID      128
#define PREDL    12
#define OBSL     8
#define BM       64
#define NTHREADS 512
#define KPAD     136    // bf16 elems per plane row (128 + 8 pad) -> 272B stride

typedef __attribute__((ext_vector_type(8))) short s16x8;
typedef __attribute__((ext_vector_type(4))) float f32x4;

#define MFMA16(a, b, c) __builtin_amdgcn_mfma_f32_16x16x32_bf16((a), (b), (c), 0, 0, 0)

__device__ __forceinline__ unsigned int cvt_pk(float a, float b) {
    unsigned int r;
    asm("v_cvt_pk_bf16_f32 %0, %1, %2" : "=v"(r) : "v"(a), "v"(b));
    return r;  // [15:0] = bf16(a), [31:16] = bf16(b)
}
__device__ __forceinline__ float ubf(unsigned int bits) { return __uint_as_float(bits); }
__device__ __forceinline__ float bf2f(short h) {
    return __uint_as_float(((unsigned int)(unsigned short)h) << 16);
}

union Frag { unsigned int u[4]; s16x8 v; };

// split 8 consecutive fp32 into hi/lo bf16x8 fragments
__device__ __forceinline__ void split8(const float* x, s16x8& hi, s16x8& lo) {
    Frag H, L;
#pragma unroll
    for (int i = 0; i < 4; ++i) {
        unsigned int hp = cvt_pk(x[2 * i], x[2 * i + 1]);
        float r0 = x[2 * i]     - ubf(hp << 16);
        float r1 = x[2 * i + 1] - ubf(hp & 0xffff0000u);
        H.u[i] = hp;
        L.u[i] = cvt_pk(r0, r1);
    }
    hi = H.v; lo = L.v;
}

// tanh(x) = 1 - 2/(exp(2x)+1): v_exp + v_rcp, ~1e-6 err (baseline-validated)
__device__ __forceinline__ float fast_tanh(float x) {
    float e = __expf(x + x);
    float r = __builtin_amdgcn_rcpf(e + 1.0f);
    return fmaf(-2.0f, r, 1.0f);
}

// Load one 128x128 weight matrix's A-fragments for this wave (rows n0..n0+15),
// split into hi/lo. Per lane: row n0+(l&15), k = kt*32 + (l>>4)*8 .. +7.
__device__ __forceinline__ void load_w(const float* __restrict__ W, int ldw,
                                       int n0, int lane, s16x8* hi, s16x8* lo) {
    const float* base = W + (size_t)(n0 + (lane & 15)) * ldw + ((lane >> 4) * 8);
#pragma unroll
    for (int kt = 0; kt < 4; ++kt) {
        float x[8];
        *(float4*)(x)     = *(const float4*)(base + kt * 32);
        *(float4*)(x + 4) = *(const float4*)(base + kt * 32 + 4);
        split8(x, hi[kt], lo[kt]);
    }
}

// acc[g] += W (this wave's 16 n-rows) x h (B from LDS hi/lo planes), 3-term split
__device__ __forceinline__ void mat_pass(f32x4* acc,
                                         const s16x8* whi, const s16x8* wlo,
                                         const unsigned short (*__restrict__ phi)[KPAD],
                                         const unsigned short (*__restrict__ plo)[KPAD],
                                         int lane) {
#pragma unroll
    for (int kt = 0; kt < 4; ++kt) {
        const int kb = kt * 32 + ((lane >> 4) * 8);
#pragma unroll
        for (int g = 0; g < 4; ++g) {
            const int m = g * 16 + (lane & 15);
            s16x8 bh = *reinterpret_cast<const s16x8*>(&phi[m][kb]);
            s16x8 bl = *reinterpret_cast<const s16x8*>(&plo[m][kb]);
            acc[g] = MFMA16(whi[kt], bh, acc[g]);
            acc[g] = MFMA16(whi[kt], bl, acc[g]);
            acc[g] = MFMA16(wlo[kt], bh, acc[g]);
        }
    }
}

__global__ void __launch_bounds__(NTHREADS, 2)
rnn_head_kernel(const float* __restrict__ raw_ctx,
                const float* __restrict__ obs_traj,
                const float* __restrict__ Wih0, const float* __restrict__ Whh0,
                const float* __restrict__ bih0, const float* __restrict__ bhh0,
                const float* __restrict__ Wih1, const float* __restrict__ Whh1,
                const float* __restrict__ bih1, const float* __restrict__ bhh1,
                const float* __restrict__ Wih2, const float* __restrict__ Whh2,
                const float* __restrict__ bih2, const float* __restrict__ bhh2,
                const float* __restrict__ fcW,  const float* __restrict__ fcb,
                float* __restrict__ out)
{
    __shared__ unsigned short h_hi[3][BM][KPAD];   // 52.2 KB
    __shared__ unsigned short h_lo[3][BM][KPAD];   // 52.2 KB
    __shared__ float pbuf[BM][2];                  // current positions
    __shared__ float fcw_s[2][HID];                // fc weights, fp32
    __shared__ __align__(16) float ctx_s[BM][132]; // prologue ctx staging, 33.8 KB

    const int tid  = threadIdx.x;
    const int lane = tid & 63;
    const int wid  = __builtin_amdgcn_readfirstlane(tid >> 6);
    const int n0   = wid * 16;                 // this wave's n-slice base
    const int row0 = blockIdx.x * BM;
    const int i15  = lane & 15;
    const int h4   = lane >> 4;                // 0..3
    const int nb   = n0 + h4 * 4;              // base of this lane's 4 D-rows (n)

    // ---------- prologue: per-lane fp32 constants ----------
    f32x4 b0, b1, b2, wp0, wp1;
#pragma unroll
    for (int r = 0; r < 4; ++r) {
        b0[r]  = bih0[nb + r] + bhh0[nb + r];
        b1[r]  = bih1[nb + r] + bhh1[nb + r];
        b2[r]  = bih2[nb + r] + bhh2[nb + r];
        wp0[r] = Wih0[(size_t)(nb + r) * INF + 512];
        wp1[r] = Wih0[(size_t)(nb + r) * INF + 513];
    }
    const float fcb0 = fcb[0], fcb1 = fcb[1];

    // ---------- init LDS: zero h planes, pbuf from obs_traj, stage fcW ----------
    for (int i = tid; i < 3 * BM * KPAD / 2; i += NTHREADS) {
        ((unsigned int*)h_hi)[i] = 0u;
        ((unsigned int*)h_lo)[i] = 0u;
    }
    if (tid < BM) {
        const float2 pv = *reinterpret_cast<const float2*>(
            &obs_traj[((size_t)(OBSL - 1) * BATCH + row0 + tid) * 2]);
        pbuf[tid][0] = pv.x; pbuf[tid][1] = pv.y;
    }
    if (tid < 2 * HID) fcw_s[tid >> 7][tid & 127] = fcW[tid];

    // ---------- ctx projection: ctxc = b0 + raw_ctx @ Wih0[:, :512].T ----------
    f32x4 ctxc[4];
#pragma unroll
    for (int g = 0; g < 4; ++g) ctxc[g] = b0;

#pragma unroll 1
    for (int kc = 0; kc < CTXF; kc += 128) {
        // A-side: Wih0 chunk fragments from global (per-lane addresses, L2-served)
        s16x8 cah[4], cal[4];
        {
            const float* base = Wih0 + (size_t)(n0 + i15) * INF + kc + h4 * 8;
#pragma unroll
            for (int kt = 0; kt < 4; ++kt) {
                float x[8];
                *(float4*)(x)     = *(const float4*)(base + kt * 32);
                *(float4*)(x + 4) = *(const float4*)(base + kt * 32 + 4);
                split8(x, cah[kt], cal[kt]);
            }
        }
        __syncthreads();   // previous chunk's ctx_s reads done
        {   // stage 64x128 fp32 chunk, coalesced
            const int rr = tid >> 3, seg = (tid & 7) * 16;
            const float* src = raw_ctx + (size_t)(row0 + rr) * CTXF + kc + seg;
            float4 v0 = ((const float4*)src)[0], v1 = ((const float4*)src)[1];
            float4 v2 = ((const float4*)src)[2], v3 = ((const float4*)src)[3];
            float* dst = &ctx_s[rr][seg];
            ((float4*)dst)[0] = v0; ((float4*)dst)[1] = v1;
            ((float4*)dst)[2] = v2; ((float4*)dst)[3] = v3;
        }
        __syncthreads();
        // B-side: read fp32, split, MFMA
#pragma unroll
        for (int kt = 0; kt < 4; ++kt) {
#pragma unroll
            for (int g = 0; g < 4; ++g) {
                const int m = g * 16 + i15;
                const float* xp = &ctx_s[m][kt * 32 + h4 * 8];
                float x[8];
                *(float4*)(x)     = *(const float4*)(xp);
                *(float4*)(x + 4) = *(const float4*)(xp + 4);
                s16x8 bh, bl;
                split8(x, bh, bl);
                ctxc[g] = MFMA16(cah[kt], bh, ctxc[g]);
                ctxc[g] = MFMA16(cah[kt], bl, ctxc[g]);
                ctxc[g] = MFMA16(cal[kt], bh, ctxc[g]);
            }
        }
    }

    // ---------- persistent weight fragments (160 VGPRs) ----------
    s16x8 whh0h[4], whh0l[4], wih1h[4], wih1l[4], whh1h[4], whh1l[4];
    s16x8 wih2h[4], wih2l[4], whh2h[4], whh2l[4];
    load_w(Whh0, HID, n0, lane, whh0h, whh0l);
    load_w(Wih1, HID, n0, lane, wih1h, wih1l);
    load_w(Whh1, HID, n0, lane, whh1h, whh1l);
    load_w(Wih2, HID, n0, lane, wih2h, wih2l);
    load_w(Whh2, HID, n0, lane, whh2h, whh2l);

    __syncthreads();   // h planes zeroed + pbuf/fcw visible

    // ---------- 12 recurrent steps ----------
#pragma unroll 1
    for (int s = 0; s < PREDL; ++s) {
        f32x4 acc[4];

        // ===== layer 0: tanh(ctxc + pos-terms + Whh0 @ h0_old) =====
#pragma unroll
        for (int g = 0; g < 4; ++g) {
            acc[g] = ctxc[g];
            const float2 p = *reinterpret_cast<const float2*>(&pbuf[g * 16 + i15][0]);
#pragma unroll
            for (int r = 0; r < 4; ++r) {
                acc[g][r] = fmaf(p.x, wp0[r], acc[g][r]);
                acc[g][r] = fmaf(p.y, wp1[r], acc[g][r]);
            }
        }
        mat_pass(acc, whh0h, whh0l, h_hi[0], h_lo[0], lane);
        __syncthreads();   // all waves done reading h0_old
#pragma unroll
        for (int g = 0; g < 4; ++g) {
            const int m = g * 16 + i15;
            float t0 = fast_tanh(acc[g][0]), t1 = fast_tanh(acc[g][1]);
            float t2 = fast_tanh(acc[g][2]), t3 = fast_tanh(acc[g][3]);
            unsigned int hp0 = cvt_pk(t0, t1), hp1 = cvt_pk(t2, t3);
            unsigned int lp0 = cvt_pk(t0 - ubf(hp0 << 16), t1 - ubf(hp0 & 0xffff0000u));
            unsigned int lp1 = cvt_pk(t2 - ubf(hp1 << 16), t3 - ubf(hp1 & 0xffff0000u));
            *reinterpret_cast<uint2*>(&h_hi[0][m][nb]) = make_uint2(hp0, hp1);
            *reinterpret_cast<uint2*>(&h_lo[0][m][nb]) = make_uint2(lp0, lp1);
        }
        __syncthreads();   // h0_new visible

        // ===== layer 1: tanh(b1 + Wih1 @ h0_new + Whh1 @ h1_old) =====
#pragma unroll
        for (int g = 0; g < 4; ++g) {
#pragma unroll
            for (int r = 0; r < 4; ++r) acc[g][r] = b1[r];
        }
        mat_pass(acc, wih1h, wih1l, h_hi[0], h_lo[0], lane);
        mat_pass(acc, whh1h, whh1l, h_hi[1], h_lo[1], lane);
        __syncthreads();
#pragma unroll
        for (int g = 0; g < 4; ++g) {
            const int m = g * 16 + i15;
            float t0 = fast_tanh(acc[g][0]), t1 = fast_tanh(acc[g][1]);
            float t2 = fast_tanh(acc[g][2]), t3 = fast_tanh(acc[g][3]);
            unsigned int hp0 = cvt_pk(t0, t1), hp1 = cvt_pk(t2, t3);
            unsigned int lp0 = cvt_pk(t0 - ubf(hp0 << 16), t1 - ubf(hp0 & 0xffff0000u));
            unsigned int lp1 = cvt_pk(t2 - ubf(hp1 << 16), t3 - ubf(hp1 & 0xffff0000u));
            *reinterpret_cast<uint2*>(&h_hi[1][m][nb]) = make_uint2(hp0, hp1);
            *reinterpret_cast<uint2*>(&h_lo[1][m][nb]) = make_uint2(lp0, lp1);
        }
        __syncthreads();

        // ===== layer 2: tanh(b2 + Wih2 @ h1_new + Whh2 @ h2_old) =====
#pragma unroll
        for (int g = 0; g < 4; ++g) {
#pragma unroll
            for (int r = 0; r < 4; ++r) acc[g][r] = b2[r];
        }
        mat_pass(acc, wih2h, wih2l, h_hi[1], h_lo[1], lane);
        mat_pass(acc, whh2h, whh2l, h_hi[2], h_lo[2], lane);
        __syncthreads();
#pragma unroll
        for (int g = 0; g < 4; ++g) {
            const int m = g * 16 + i15;
            float t0 = fast_tanh(acc[g][0]), t1 = fast_tanh(acc[g][1]);
            float t2 = fast_tanh(acc[g][2]), t3 = fast_tanh(acc[g][3]);
            unsigned int hp0 = cvt_pk(t0, t1), hp1 = cvt_pk(t2, t3);
            unsigned int lp0 = cvt_pk(t0 - ubf(hp0 << 16), t1 - ubf(hp0 & 0xffff0000u));
            unsigned int lp1 = cvt_pk(t2 - ubf(hp1 << 16), t3 - ubf(hp1 & 0xffff0000u));
            *reinterpret_cast<uint2*>(&h_hi[2][m][nb]) = make_uint2(hp0, hp1);
            *reinterpret_cast<uint2*>(&h_lo[2][m][nb]) = make_uint2(lp0, lp1);
        }
        __syncthreads();

        // ===== fc: out[m][c] = fcb[c] + h2[m] . fcW[c]  (waves 0/1, fp32 VALU) =====
        if (wid < 2) {
            const int m = lane, c = wid;
            float o = (c == 0) ? fcb0 : fcb1;
#pragma unroll
            for (int kb = 0; kb < HID; kb += 8) {
                s16x8 hv = *reinterpret_cast<const s16x8*>(&h_hi[2][m][kb]);
                s16x8 lv = *reinterpret_cast<const s16x8*>(&h_lo[2][m][kb]);
                float wv[8];
                *(float4*)(wv)     = *(const float4*)(&fcw_s[c][kb]);
                *(float4*)(wv + 4) = *(const float4*)(&fcw_s[c][kb + 4]);
#pragma unroll
                for (int j = 0; j < 8; ++j) {
                    float x = bf2f(hv[j]) + bf2f(lv[j]);
                    o = fmaf(x, wv[j], o);
                }
            }
            pbuf[m][c] = o;
            out[((size_t)s * BATCH + row0 + m) * 2 + c] = o;
        }
        __syncthreads();   // pbuf visible for next step's layer 0
    }
}

extern "C" void kernel_launch(void* const* d_in, const int* in_sizes, int n_in,
                              void* d_out, int out_size, void* d_ws, size_t ws_size,
                              hipStream_t stream)
{
    const float* raw_ctx  = (const float*)d_in[0];
    const float* obs_traj = (const float*)d_in[1];
    const float* Wih0 = (const float*)d_in[2];
    const float* Whh0 = (const float*)d_in[3];
    const float* bih0 = (const float*)d_in[4];
    const float* bhh0 = (const float*)d_in[5];
    const float* Wih1 = (const float*)d_in[6];
    const float* Whh1 = (const float*)d_in[7];
    const float* bih1 = (const float*)d_in[8];
    const float* bhh1 = (const float*)d_in[9];
    const float* Wih2 = (const float*)d_in[10];
    const float* Whh2 = (const float*)d_in[11];
    const float* bih2 = (const float*)d_in[12];
    const float* bhh2 = (const float*)d_in[13];
    const float* fcW  = (const float*)d_in[14];
    const float* fcb  = (const float*)d_in[15];
    float* out = (float*)d_out;

    dim3 grid(BATCH / BM);   // 1024 blocks
    dim3 block(NTHREADS);    // 512 threads = 8 waves
    rnn_head_kernel<<<grid, block, 0, stream>>>(
        raw_ctx, obs_traj,
        Wih0, Whh0, bih0, bhh0,
        Wih1, Whh1, bih1, bhh1,
        Wih2, Whh2, bih2, bhh2,
        fcW, fcb, out);
}